// Round 5
// baseline (445.820 us; speedup 1.0000x reference)
//
#include <hip/hip_runtime.h>

#define NP1 20000
#define NP2 80000
#define KN  27

typedef unsigned short ushort;
typedef unsigned int   uint;
typedef __attribute__((ext_vector_type(8))) short short8v;
typedef __attribute__((ext_vector_type(4))) float f32x4;

__device__ __forceinline__ ushort f2bf(float x) {
    union { float f; uint u; } v; v.f = x;
    uint r = v.u + 0x7fffu + ((v.u >> 16) & 1u);
    return (ushort)(r >> 16);
}
__device__ __forceinline__ float bf2f(ushort s) {
    union { uint u; float f; } v; v.u = ((uint)s) << 16;
    return v.f;
}
__device__ __forceinline__ void gload_lds16(const void* g, void* l) {
    __builtin_amdgcn_global_load_lds(
        (const __attribute__((address_space(1))) unsigned int*)g,
        (__attribute__((address_space(3))) unsigned int*)l, 16, 0, 0);
}
template<int N> __device__ __forceinline__ void wait_vmcnt() {
    if constexpr (N == 0)       asm volatile("s_waitcnt vmcnt(0)" ::: "memory");
    else if constexpr (N == 6)  asm volatile("s_waitcnt vmcnt(6)" ::: "memory");
    else if constexpr (N == 8)  asm volatile("s_waitcnt vmcnt(8)" ::: "memory");
    else if constexpr (N == 10) asm volatile("s_waitcnt vmcnt(10)" ::: "memory");
    else if constexpr (N == 12) asm volatile("s_waitcnt vmcnt(12)" ::: "memory");
}

// ---------------------------------------------------------------------------
// prep kernels (weights -> bf16, transposed, chunk-swizzled)
// ---------------------------------------------------------------------------
__global__ __launch_bounds__(256) void prep_wT_k(const float* __restrict__ W,
                                                 ushort* __restrict__ dst, int ntaps)
{
    int i = blockIdx.x * 256 + threadIdx.x;
    if (i >= ntaps * 4096) return;
    int k = i >> 12, rem = i & 4095, c = rem >> 6, jj = rem & 63;
    int j = (((jj >> 3) ^ (c & 7)) << 3) | (jj & 7);
    dst[i] = f2bf(W[(size_t)k * 4096 + j * 64 + c]);
}
__global__ __launch_bounds__(256) void prep_wbT_k(const float* __restrict__ W,
                                                  ushort* __restrict__ dst)
{
    int i = blockIdx.x * 256 + threadIdx.x;
    if (i >= 1024) return;
    int c = i >> 6, jj = i & 63;
    int j = (((jj >> 3) ^ (c & 7)) << 3) | (jj & 7);
    dst[i] = f2bf(W[j * 16 + c]);
}
__global__ __launch_bounds__(256) void prep_s1_k(const float* __restrict__ s,
                                                 ushort* __restrict__ dst)
{
    int i = blockIdx.x * 256 + threadIdx.x;
    if (i >= 1024) return;
    int e = i >> 6, jj = i & 63;
    int j = (((jj >> 3) ^ (e & 7)) << 3) | (jj & 7);
    dst[i] = f2bf(s[e * 64 + j]);
}

// ---------------------------------------------------------------------------
// gathers
// ---------------------------------------------------------------------------
__global__ __launch_bounds__(256) void gather_curr_k(
    const float* __restrict__ prior_emb, const int* __restrict__ curr_occ,
    ushort* __restrict__ out)
{
    int i = blockIdx.x * 256 + threadIdx.x;
    if (i >= NP1 * 32) return;
    int row = i >> 5, cp = (i & 31) * 2;
    const float* src = prior_emb + (size_t)curr_occ[row] * 64 + cp;
    uint pk = (uint)f2bf(src[0]) | ((uint)f2bf(src[1]) << 16);
    *(uint*)((char*)out + (size_t)row * 128 + cp * 2) = pk;
}

__global__ __launch_bounds__(256) void gather_next_k(
    const ushort* __restrict__ f, const int* __restrict__ parent_idx,
    const int* __restrict__ next_oct, const float* __restrict__ temb8,
    ushort* __restrict__ out)
{
    int i = blockIdx.x * 256 + threadIdx.x;
    if (i >= NP2 * 32) return;
    int row = i >> 5, cp = (i & 31) * 2;
    const ushort* fs = f + (size_t)parent_idx[row] * 64 + cp;
    const float* ts = temb8 + (size_t)next_oct[row] * 64 + cp;
    float v0 = bf2f(fs[0]) + ts[0];
    float v1 = bf2f(fs[1]) + ts[1];
    uint pk = (uint)f2bf(v0) | ((uint)f2bf(v1) << 16);
    *(uint*)((char*)out + (size_t)row * 128 + cp * 2) = pk;
}

// ---------------------------------------------------------------------------
// 3-buffer counted-vmcnt pipelined MFMA sparse conv (dynamic LDS).
// Per tap k: {load idx(k+2)} {stage(k+1)->buf[(k+1)%3]} vmcnt(VMC) barrier
//            MFMA on buf[k%3].  Stage loads stay in flight ACROSS the barrier.
// 3 buffers required: stage(k+1) writes a buffer last read at compute(k-2),
// which all waves finished before barrier(k-1) < stage-issue(k+1).
// ---------------------------------------------------------------------------
template<int NW, int MB>
__global__ __launch_bounds__(NW * 64) void spconv_pipe_k(
    const ushort* __restrict__ feats, const int* __restrict__ nbr,
    const ushort* __restrict__ Wsw, const ushort* __restrict__ res,
    ushort* __restrict__ out, const ushort* __restrict__ zpage)
{
    constexpr int ROWS   = NW * MB * 16;
    constexpr int RPW    = MB * 16;
    constexpr int GB     = ROWS * 128;
    constexpr int BUFB   = GB + 8192;
    constexpr int GLOADS = GB / (NW * 64 * 16);
    constexpr int WLOADS = 8192 / (NW * 64 * 16);
    constexpr int VMC    = WLOADS + 2 * GLOADS;  // steady-state wait
    constexpr int VMT    = WLOADS + GLOADS;      // tail (no idx issued)

    extern __shared__ __align__(16) char sm[];   // 3 * BUFB bytes

    const int t = threadIdx.x;
    const int w = t >> 6, l = t & 63;
    const int row0 = blockIdx.x * ROWS;
    const int lr = l & 15, lhi = l >> 4;
    const int chbase = lr & 7;
    const int srcswz = (((l & 7) ^ (l >> 3)) << 4);

    const int* nbp[GLOADS];
    #pragma unroll
    for (int i = 0; i < GLOADS; ++i) {
        int rt = w * RPW + i * 8 + (l >> 3);
        nbp[i] = nbr + (size_t)(row0 + rt) * KN;
    }

    f32x4 acc[MB][4];
    #pragma unroll
    for (int a = 0; a < MB; ++a)
        #pragma unroll
        for (int b = 0; b < 4; ++b) acc[a][b] = (f32x4)0.0f;

    int idxA[GLOADS], idxB[GLOADS];

    // ---- prologue: idx(1) first (older than stage(0)), then stage tap 0 ----
    {
        int idx0[GLOADS];
        #pragma unroll
        for (int i = 0; i < GLOADS; ++i) idx0[i] = nbp[i][0];
        #pragma unroll
        for (int i = 0; i < GLOADS; ++i) idxA[i] = nbp[i][1];
        const char* wsrc = (const char*)Wsw;
        #pragma unroll
        for (int i = 0; i < WLOADS; ++i) {
            int off = (w * WLOADS + i) * 1024;
            gload_lds16(wsrc + off + l * 16, sm + GB + off);
        }
        #pragma unroll
        for (int i = 0; i < GLOADS; ++i) {
            const char* src = (idx0[i] >= 0)
                ? (const char*)feats + (size_t)idx0[i] * 128 + srcswz
                : (const char*)zpage + srcswz;
            gload_lds16(src, sm + (w * RPW + i * 8) * 128);
        }
        asm volatile("" ::: "memory");
    }

#define SUBITER(K, IDXUSE, IDXLOAD, DOIDX, DOSTAGE, WAITN)                     \
    {                                                                          \
        const int k_ = (K);                                                    \
        if (DOIDX) {                                                           \
            _Pragma("unroll")                                                  \
            for (int i = 0; i < GLOADS; ++i) IDXLOAD[i] = nbp[i][k_ + 2];      \
        }                                                                      \
        if (DOSTAGE) {                                                         \
            char* nxt = sm + ((k_ + 1) % 3) * BUFB;                            \
            const char* wsrc = (const char*)Wsw + (size_t)(k_ + 1) * 8192;     \
            _Pragma("unroll")                                                  \
            for (int i = 0; i < WLOADS; ++i) {                                 \
                int off = (w * WLOADS + i) * 1024;                             \
                gload_lds16(wsrc + off + l * 16, nxt + GB + off);              \
            }                                                                  \
            _Pragma("unroll")                                                  \
            for (int i = 0; i < GLOADS; ++i) {                                 \
                const char* src = (IDXUSE[i] >= 0)                             \
                    ? (const char*)feats + (size_t)IDXUSE[i] * 128 + srcswz    \
                    : (const char*)zpage + srcswz;                             \
                gload_lds16(src, nxt + (w * RPW + i * 8) * 128);               \
            }                                                                  \
        }                                                                      \
        wait_vmcnt<WAITN>();                                                   \
        __builtin_amdgcn_s_barrier();                                          \
        __builtin_amdgcn_sched_barrier(0);                                     \
        {                                                                      \
            char* cur = sm + (k_ % 3) * BUFB;                                  \
            __builtin_amdgcn_s_setprio(1);                                     \
            _Pragma("unroll")                                                  \
            for (int j0 = 0; j0 < 2; ++j0) {                                   \
                short8v af[MB], bfr[4];                                        \
                _Pragma("unroll")                                              \
                for (int mb = 0; mb < MB; ++mb) {                              \
                    int r = w * RPW + mb * 16 + lr;                            \
                    int ch = (j0 * 4 + lhi) ^ chbase;                          \
                    af[mb] = *(const short8v*)(cur + r * 128 + ch * 16);       \
                }                                                              \
                _Pragma("unroll")                                              \
                for (int nb = 0; nb < 4; ++nb) {                               \
                    int c = nb * 16 + lr;                                      \
                    int ch = (j0 * 4 + lhi) ^ chbase;                          \
                    bfr[nb] = *(const short8v*)(cur + GB + c * 128 + ch * 16); \
                }                                                              \
                _Pragma("unroll")                                              \
                for (int mb = 0; mb < MB; ++mb)                                \
                    _Pragma("unroll")                                          \
                    for (int nb = 0; nb < 4; ++nb)                             \
                        acc[mb][nb] = __builtin_amdgcn_mfma_f32_16x16x32_bf16( \
                            af[mb], bfr[nb], acc[mb][nb], 0, 0, 0);            \
            }                                                                  \
            __builtin_amdgcn_s_setprio(0);                                     \
        }                                                                      \
    }

    for (int k = 0; k < KN - 3; k += 2) {      // pairs (0,1)...(22,23)
        SUBITER(k,     idxA, idxB, true, true, VMC);
        SUBITER(k + 1, idxB, idxA, true, true, VMC);
    }
    SUBITER(KN - 3, idxA, idxB, true,  true,  VMC);   // k=24: idx(26), stage(25)
    SUBITER(KN - 2, idxB, idxA, false, true,  VMT);   // k=25: stage(26) via idxB
    SUBITER(KN - 1, idxA, idxB, false, false, 0);     // k=26: compute only
#undef SUBITER

    // ---- epilogue: +res, relu, pack 2 cols, store bf16 ----
    #pragma unroll
    for (int mb = 0; mb < MB; ++mb) {
        #pragma unroll
        for (int nb = 0; nb < 4; ++nb) {
            #pragma unroll
            for (int r = 0; r < 4; ++r) {
                int rg = row0 + w * RPW + mb * 16 + lhi * 4 + r;
                int c = nb * 16 + lr;
                float v = acc[mb][nb][r];
                if (res != nullptr) v += bf2f(res[(size_t)rg * 64 + c]);
                v = fmaxf(v, 0.0f);
                float o = __shfl_xor(v, 1);
                if (!(l & 1)) {
                    uint pk = (uint)f2bf(v) | ((uint)f2bf(o) << 16);
                    *(uint*)((char*)out + (size_t)rg * 128 + (c << 1)) = pk;
                }
            }
        }
    }
}

// ---------------------------------------------------------------------------
// MFMA head with lane-parallel softmax (LDS transpose of logits)
// ---------------------------------------------------------------------------
__global__ __launch_bounds__(256) void head_mfma_k(
    const ushort* __restrict__ G, const int* __restrict__ next_occ,
    const ushort* __restrict__ Wsmall,
    const float* __restrict__ b0a, const float* __restrict__ b1a,
    const float* __restrict__ b0b, const float* __restrict__ b1b,
    const int* __restrict__ n_points, float* __restrict__ outp)
{
    __shared__ __align__(16) char sm[32768 + 22528 + 640 + 8704];
    char* sG = sm;
    char* sH = sm + 16384;
    char* sWs = sm + 32768;
    float* sBf = (float*)(sm + 32768 + 22528);
    float* sL  = (float*)(sm + 32768 + 22528 + 640);   // [128][17] f32

    const int t = threadIdx.x;
    const int w = t >> 6, l = t & 63;
    const int row0 = blockIdx.x * 128;
    const int lr = l & 15, lhi = l >> 4;
    const int wr0 = w * 32;
    const int myrow = wr0 + (l & 31);
    const int occ_l = next_occ[row0 + myrow];

    #pragma unroll
    for (int i = 0; i < 4; ++i) {
        int rt = w * 32 + i * 8 + (l >> 3);
        int row = row0 + rt;
        gload_lds16((const char*)G + (size_t)row * 128 + (((l & 7) ^ (rt & 7)) << 4),
                    sG + (w * 32 + i * 8) * 128);
    }
    for (int i = w; i < 22; i += 4)
        gload_lds16((const char*)Wsmall + i * 1024 + l * 16, sWs + i * 1024);
    if (t < 64)                 sBf[t] = b0a[t];
    else if (t < 128)           sBf[t] = b1a[t - 64];
    else if (t < 144)           sBf[128 + (t - 128)] = b0b[t - 128];
    else if (t < 160)           sBf[144 + (t - 144)] = b1b[t - 144];
    __syncthreads();

    float bacc = 0.0f;
    f32x4 lg[2];

    // ======== stage 0 ========
    {
        f32x4 acc[2][4];
        #pragma unroll
        for (int a = 0; a < 2; ++a)
            #pragma unroll
            for (int b = 0; b < 4; ++b) acc[a][b] = (f32x4)0.0f;
        #pragma unroll
        for (int j0 = 0; j0 < 2; ++j0) {
            short8v a[2], b[4];
            #pragma unroll
            for (int mb = 0; mb < 2; ++mb) {
                int r = wr0 + mb * 16 + lr;
                int ch = (j0 * 4 + lhi) ^ (r & 7);
                a[mb] = *(const short8v*)(sG + r * 128 + ch * 16);
            }
            #pragma unroll
            for (int nb = 0; nb < 4; ++nb) {
                int c = nb * 16 + lr;
                int ch = (j0 * 4 + lhi) ^ (c & 7);
                b[nb] = *(const short8v*)(sWs + c * 128 + ch * 16);   // W0aT
            }
            #pragma unroll
            for (int mb = 0; mb < 2; ++mb)
                #pragma unroll
                for (int nb = 0; nb < 4; ++nb)
                    acc[mb][nb] = __builtin_amdgcn_mfma_f32_16x16x32_bf16(
                        a[mb], b[nb], acc[mb][nb], 0, 0, 0);
        }
        #pragma unroll
        for (int mb = 0; mb < 2; ++mb)
            #pragma unroll
            for (int nb = 0; nb < 4; ++nb) {
                float bias = sBf[nb * 16 + lr];
                #pragma unroll
                for (int r = 0; r < 4; ++r) {
                    int row = wr0 + mb * 16 + lhi * 4 + r;
                    int j = nb * 16 + lr;
                    float v = fmaxf(acc[mb][nb][r] + bias, 0.0f);
                    float o = __shfl_xor(v, 1);
                    if (!(l & 1)) {
                        uint pk = (uint)f2bf(v) | ((uint)f2bf(o) << 16);
                        *(uint*)(sH + row * 128 + (((j >> 3) ^ (row & 7)) << 4)
                                 + (j & 7) * 2) = pk;
                    }
                }
            }
        lg[0] = (f32x4)0.0f; lg[1] = (f32x4)0.0f;
        #pragma unroll
        for (int j0 = 0; j0 < 2; ++j0) {
            short8v a[2], b;
            #pragma unroll
            for (int mb = 0; mb < 2; ++mb) {
                int r = wr0 + mb * 16 + lr;
                int ch = (j0 * 4 + lhi) ^ (r & 7);
                a[mb] = *(const short8v*)(sH + r * 128 + ch * 16);
            }
            {
                int c = lr;
                int ch = (j0 * 4 + lhi) ^ (c & 7);
                b = *(const short8v*)(sWs + 16384 + c * 128 + ch * 16); // W0bT
            }
            #pragma unroll
            for (int mb = 0; mb < 2; ++mb)
                lg[mb] = __builtin_amdgcn_mfma_f32_16x16x32_bf16(a[mb], b, lg[mb], 0, 0, 0);
        }
        #pragma unroll
        for (int mb = 0; mb < 2; ++mb)
            #pragma unroll
            for (int r = 0; r < 4; ++r)
                sL[(wr0 + mb * 16 + lhi * 4 + r) * 17 + lr] = lg[mb][r] + sBf[128 + lr];
        asm volatile("s_waitcnt lgkmcnt(0)" ::: "memory");
        __builtin_amdgcn_sched_barrier(0);
        {
            int tgt = occ_l & 15;
            float lv[16], mx = -1e30f;
            #pragma unroll
            for (int c = 0; c < 16; ++c) {
                lv[c] = sL[myrow * 17 + c];
                mx = fmaxf(mx, lv[c]);
            }
            float ssum = 0.0f, lt = lv[0];
            #pragma unroll
            for (int c = 0; c < 16; ++c) {
                ssum += __expf(lv[c] - mx);
                lt = (c == tgt) ? lv[c] : lt;
            }
            float p = __expf(lt - mx) / ssum;
            float bits = fminf(fmaxf(-log2f(p + 1e-10f), 0.0f), 50.0f);
            if (l < 32) bacc += bits;
        }
    }

    // ======== stage 1 ========
    {
        f32x4 acc1[2][4];
        #pragma unroll
        for (int a = 0; a < 2; ++a)
            #pragma unroll
            for (int b = 0; b < 4; ++b) acc1[a][b] = (f32x4)0.0f;
        #pragma unroll
        for (int j0 = 0; j0 < 2; ++j0) {
            short8v a[2], b[4];
            #pragma unroll
            for (int mb = 0; mb < 2; ++mb) {
                int rloc = wr0 + mb * 16 + lr;
                int low = next_occ[row0 + rloc] & 15;
                int ch = (j0 * 4 + lhi) ^ (rloc & 7);
                short8v g8 = *(const short8v*)(sG + rloc * 128 + ch * 16);
                int che = (j0 * 4 + lhi) ^ (low & 7);
                short8v e8 = *(const short8v*)(sWs + 20480 + low * 128 + che * 16); // s1b
                #pragma unroll
                for (int e = 0; e < 8; ++e) {
                    float f = bf2f((ushort)g8[e]) + bf2f((ushort)e8[e]);
                    a[mb][e] = (short)f2bf(f);
                }
            }
            #pragma unroll
            for (int nb = 0; nb < 4; ++nb) {
                int c = nb * 16 + lr;
                int ch = (j0 * 4 + lhi) ^ (c & 7);
                b[nb] = *(const short8v*)(sWs + 8192 + c * 128 + ch * 16);  // W1aT
            }
            #pragma unroll
            for (int mb = 0; mb < 2; ++mb)
                #pragma unroll
                for (int nb = 0; nb < 4; ++nb)
                    acc1[mb][nb] = __builtin_amdgcn_mfma_f32_16x16x32_bf16(
                        a[mb], b[nb], acc1[mb][nb], 0, 0, 0);
        }
        #pragma unroll
        for (int mb = 0; mb < 2; ++mb)
            #pragma unroll
            for (int nb = 0; nb < 4; ++nb) {
                float bias = sBf[64 + nb * 16 + lr];
                #pragma unroll
                for (int r = 0; r < 4; ++r) {
                    int row = wr0 + mb * 16 + lhi * 4 + r;
                    int j = nb * 16 + lr;
                    float v = fmaxf(acc1[mb][nb][r] + bias, 0.0f);
                    float o = __shfl_xor(v, 1);
                    if (!(l & 1)) {
                        uint pk = (uint)f2bf(v) | ((uint)f2bf(o) << 16);
                        *(uint*)(sH + row * 128 + (((j >> 3) ^ (row & 7)) << 4)
                                 + (j & 7) * 2) = pk;
                    }
                }
            }
        lg[0] = (f32x4)0.0f; lg[1] = (f32x4)0.0f;
        #pragma unroll
        for (int j0 = 0; j0 < 2; ++j0) {
            short8v a[2], b;
            #pragma unroll
            for (int mb = 0; mb < 2; ++mb) {
                int r = wr0 + mb * 16 + lr;
                int ch = (j0 * 4 + lhi) ^ (r & 7);
                a[mb] = *(const short8v*)(sH + r * 128 + ch * 16);
            }
            {
                int c = lr;
                int ch = (j0 * 4 + lhi) ^ (c & 7);
                b = *(const short8v*)(sWs + 18432 + c * 128 + ch * 16); // W1bT
            }
            #pragma unroll
            for (int mb = 0; mb < 2; ++mb)
                lg[mb] = __builtin_amdgcn_mfma_f32_16x16x32_bf16(a[mb], b, lg[mb], 0, 0, 0);
        }
        #pragma unroll
        for (int mb = 0; mb < 2; ++mb)
            #pragma unroll
            for (int r = 0; r < 4; ++r)
                sL[(wr0 + mb * 16 + lhi * 4 + r) * 17 + lr] = lg[mb][r] + sBf[144 + lr];
        asm volatile("s_waitcnt lgkmcnt(0)" ::: "memory");
        __builtin_amdgcn_sched_barrier(0);
        {
            int tgt = occ_l >> 4;
            float lv[16], mx = -1e30f;
            #pragma unroll
            for (int c = 0; c < 16; ++c) {
                lv[c] = sL[myrow * 17 + c];
                mx = fmaxf(mx, lv[c]);
            }
            float ssum = 0.0f, lt = lv[0];
            #pragma unroll
            for (int c = 0; c < 16; ++c) {
                ssum += __expf(lv[c] - mx);
                lt = (c == tgt) ? lv[c] : lt;
            }
            float p = __expf(lt - mx) / ssum;
            float bits = fminf(fmaxf(-log2f(p + 1e-10f), 0.0f), 50.0f);
            if (l < 32) bacc += bits;
        }
    }

    #pragma unroll
    for (int s = 1; s < 64; s <<= 1) bacc += __shfl_xor(bacc, s);
    if (l == 0) atomicAdd(outp, bacc / (float)(*n_points));
}

// ---------------------------------------------------------------------------
extern "C" void kernel_launch(void* const* d_in, const int* in_sizes, int n_in,
                              void* d_out, int out_size, void* d_ws, size_t ws_size,
                              hipStream_t stream)
{
    const float* prior_emb = (const float*)d_in[0];
    const float* temb8     = (const float*)d_in[1];
    const float* Wp        = (const float*)d_in[2];
    const float* Wt        = (const float*)d_in[3];
    const float* W0a       = (const float*)d_in[4];
    const float* b0a       = (const float*)d_in[5];
    const float* W0b       = (const float*)d_in[6];
    const float* b0b       = (const float*)d_in[7];
    const float* W1a       = (const float*)d_in[8];
    const float* b1a       = (const float*)d_in[9];
    const float* W1b       = (const float*)d_in[10];
    const float* b1b       = (const float*)d_in[11];
    const float* s1_emb    = (const float*)d_in[12];
    const int*   curr_occ  = (const int*)d_in[13];
    const int*   next_occ  = (const int*)d_in[14];
    const int*   next_oct  = (const int*)d_in[15];
    const int*   parent    = (const int*)d_in[16];
    const int*   nbr_curr  = (const int*)d_in[17];
    const int*   nbr_next  = (const int*)d_in[18];
    const int*   n_points  = (const int*)d_in[19];
    float* out = (float*)d_out;

    char* wsb = (char*)d_ws;
    ushort* zpage = (ushort*)wsb;
    size_t off = 256;
    ushort* WpT = (ushort*)(wsb + off); off += (size_t)135 * 4096 * 2;
    ushort* WtT = (ushort*)(wsb + off); off += (size_t)135 * 4096 * 2;
    ushort* Wsmall = (ushort*)(wsb + off);
    ushort* W0aT = Wsmall;
    ushort* W1aT = Wsmall + 4096;
    ushort* W0bT = Wsmall + 8192;
    ushort* W1bT = Wsmall + 9216;
    ushort* s1bT = Wsmall + 10240;
    off += 11264 * 2;
    off = (off + 255) & ~(size_t)255;
    ushort* fA = (ushort*)(wsb + off); off += (size_t)NP1 * 64 * 2;
    ushort* fB = (ushort*)(wsb + off); off += (size_t)NP1 * 64 * 2;
    ushort* fC = (ushort*)(wsb + off); off += (size_t)NP1 * 64 * 2;
    ushort* gA = (ushort*)(wsb + off); off += (size_t)NP2 * 64 * 2;
    ushort* gB = (ushort*)(wsb + off); off += (size_t)NP2 * 64 * 2;
    ushort* gC = (ushort*)(wsb + off); off += (size_t)NP2 * 64 * 2;

    hipMemsetAsync(d_out, 0, sizeof(float), stream);
    hipMemsetAsync(zpage, 0, 256, stream);

    prep_wT_k<<<(135 * 4096 + 255) / 256, 256, 0, stream>>>(Wp, WpT, 135);
    prep_wT_k<<<(135 * 4096 + 255) / 256, 256, 0, stream>>>(Wt, WtT, 135);
    prep_wT_k<<<16, 256, 0, stream>>>(W0a, W0aT, 1);
    prep_wT_k<<<16, 256, 0, stream>>>(W1a, W1aT, 1);
    prep_wbT_k<<<4, 256, 0, stream>>>(W0b, W0bT);
    prep_wbT_k<<<4, 256, 0, stream>>>(W1b, W1bT);
    prep_s1_k<<<4, 256, 0, stream>>>(s1_emb, s1bT);

    gather_curr_k<<<(NP1 * 32 + 255) / 256, 256, 0, stream>>>(prior_emb, curr_occ, fA);

    const size_t WT = (size_t)KN * 4096;
    // N1: <2,1> 32 rows, 625 blocks, dyn LDS 3*(4096+8192)=36864 (4 blk/CU)
    // N2: <4,2> 128 rows, 625 blocks, dyn LDS 3*(16384+8192)=73728 (2 blk/CU)
    constexpr size_t LDS1 = 3 * (32 * 128 + 8192);
    constexpr size_t LDS2 = 3 * (128 * 128 + 8192);

    spconv_pipe_k<2,1><<<625, 128, LDS1, stream>>>(fA, nbr_curr, WpT + 0 * WT, nullptr, fB, zpage);
    spconv_pipe_k<2,1><<<625, 128, LDS1, stream>>>(fB, nbr_curr, WpT + 1 * WT, nullptr, fC, zpage);
    spconv_pipe_k<2,1><<<625, 128, LDS1, stream>>>(fC, nbr_curr, WpT + 2 * WT, fB,      fA, zpage);
    spconv_pipe_k<2,1><<<625, 128, LDS1, stream>>>(fA, nbr_curr, WpT + 3 * WT, nullptr, fC, zpage);
    spconv_pipe_k<2,1><<<625, 128, LDS1, stream>>>(fC, nbr_curr, WpT + 4 * WT, fA,      fB, zpage);

    gather_next_k<<<(NP2 * 32 + 255) / 256, 256, 0, stream>>>(fB, parent, next_oct, temb8, gA);

    spconv_pipe_k<4,2><<<625, 256, LDS2, stream>>>(gA, nbr_next, WtT + 0 * WT, nullptr, gB, zpage);
    spconv_pipe_k<4,2><<<625, 256, LDS2, stream>>>(gB, nbr_next, WtT + 1 * WT, nullptr, gC, zpage);
    spconv_pipe_k<4,2><<<625, 256, LDS2, stream>>>(gC, nbr_next, WtT + 2 * WT, gB,      gA, zpage);
    spconv_pipe_k<4,2><<<625, 256, LDS2, stream>>>(gA, nbr_next, WtT + 3 * WT, nullptr, gC, zpage);
    spconv_pipe_k<4,2><<<625, 256, LDS2, stream>>>(gC, nbr_next, WtT + 4 * WT, gA,      gB, zpage);

    head_mfma_k<<<625, 256, 0, stream>>>(gB, next_occ, Wsmall,
                                         b0a, b1a, b0b, b1b, n_points, out);
}

// Round 6
// 329.355 us; speedup vs baseline: 1.3536x; 1.3536x over previous
//
#include <hip/hip_runtime.h>

#define NP1 20000
#define NP2 80000
#define KN  27

typedef unsigned short ushort;
typedef unsigned int   uint;
typedef __attribute__((ext_vector_type(8))) short short8v;
typedef __attribute__((ext_vector_type(4))) float f32x4;

__device__ __forceinline__ ushort f2bf(float x) {
    union { float f; uint u; } v; v.f = x;
    uint r = v.u + 0x7fffu + ((v.u >> 16) & 1u);
    return (ushort)(r >> 16);
}
__device__ __forceinline__ float bf2f(ushort s) {
    union { uint u; float f; } v; v.u = ((uint)s) << 16;
    return v.f;
}
__device__ __forceinline__ void gload_lds16(const void* g, void* l) {
    __builtin_amdgcn_global_load_lds(
        (const __attribute__((address_space(1))) unsigned int*)g,
        (__attribute__((address_space(3))) unsigned int*)l, 16, 0, 0);
}
// bijective chunked XCD swizzle (m204): consecutive blocks -> same XCD
__device__ __forceinline__ int xcd_swz(int b, int nb) {
    int q = nb >> 3, r = nb & 7;
    int x = b & 7, p = b >> 3;
    return (x < r) ? x * (q + 1) + p : r * (q + 1) + (x - r) * q + p;
}

// ---------------------------------------------------------------------------
// prep kernels (weights -> bf16, transposed, chunk-swizzled)
// ---------------------------------------------------------------------------
__global__ __launch_bounds__(256) void prep_wT_k(const float* __restrict__ W,
                                                 ushort* __restrict__ dst, int ntaps)
{
    int i = blockIdx.x * 256 + threadIdx.x;
    if (i >= ntaps * 4096) return;
    int k = i >> 12, rem = i & 4095, c = rem >> 6, jj = rem & 63;
    int j = (((jj >> 3) ^ (c & 7)) << 3) | (jj & 7);
    dst[i] = f2bf(W[(size_t)k * 4096 + j * 64 + c]);
}
__global__ __launch_bounds__(256) void prep_wbT_k(const float* __restrict__ W,
                                                  ushort* __restrict__ dst)
{
    int i = blockIdx.x * 256 + threadIdx.x;
    if (i >= 1024) return;
    int c = i >> 6, jj = i & 63;
    int j = (((jj >> 3) ^ (c & 7)) << 3) | (jj & 7);
    dst[i] = f2bf(W[j * 16 + c]);
}
__global__ __launch_bounds__(256) void prep_s1_k(const float* __restrict__ s,
                                                 ushort* __restrict__ dst)
{
    int i = blockIdx.x * 256 + threadIdx.x;
    if (i >= 1024) return;
    int e = i >> 6, jj = i & 63;
    int j = (((jj >> 3) ^ (e & 7)) << 3) | (jj & 7);
    dst[i] = f2bf(s[e * 64 + j]);
}

// ---------------------------------------------------------------------------
// gathers
// ---------------------------------------------------------------------------
__global__ __launch_bounds__(256) void gather_curr_k(
    const float* __restrict__ prior_emb, const int* __restrict__ curr_occ,
    ushort* __restrict__ out)
{
    int i = blockIdx.x * 256 + threadIdx.x;
    if (i >= NP1 * 32) return;
    int row = i >> 5, cp = (i & 31) * 2;
    const float* src = prior_emb + (size_t)curr_occ[row] * 64 + cp;
    uint pk = (uint)f2bf(src[0]) | ((uint)f2bf(src[1]) << 16);
    *(uint*)((char*)out + (size_t)row * 128 + cp * 2) = pk;
}

__global__ __launch_bounds__(256) void gather_next_k(
    const ushort* __restrict__ f, const int* __restrict__ parent_idx,
    const int* __restrict__ next_oct, const float* __restrict__ temb8,
    ushort* __restrict__ out)
{
    int i = blockIdx.x * 256 + threadIdx.x;
    if (i >= NP2 * 32) return;
    int row = i >> 5, cp = (i & 31) * 2;
    const ushort* fs = f + (size_t)parent_idx[row] * 64 + cp;
    const float* ts = temb8 + (size_t)next_oct[row] * 64 + cp;
    float v0 = bf2f(fs[0]) + ts[0];
    float v1 = bf2f(fs[1]) + ts[1];
    uint pk = (uint)f2bf(v0) | ((uint)f2bf(v1) << 16);
    *(uint*)((char*)out + (size_t)row * 128 + cp * 2) = pk;
}

// ---------------------------------------------------------------------------
// 2-buffer single-sync MFMA sparse conv (R2 structure, proven fastest):
//   iter k: sync (drains stage(k)) -> issue stage(k+1) -> prefetch idx(k+2)
//           -> MFMA on buf[k&1].
// NW waves, MB*16 rows/wave, static LDS 2*(ROWS*128 + 8192).
// XCD-chunked blockIdx swizzle keeps each XCD's gather set in its L2.
// ---------------------------------------------------------------------------
template<int NW, int MB>
__global__ __launch_bounds__(NW * 64) void spconv_db_k(
    const ushort* __restrict__ feats, const int* __restrict__ nbr,
    const ushort* __restrict__ Wsw, const ushort* __restrict__ res,
    ushort* __restrict__ out, const ushort* __restrict__ zpage, int nblocks)
{
    constexpr int ROWS   = NW * MB * 16;
    constexpr int RPW    = MB * 16;
    constexpr int GB     = ROWS * 128;
    constexpr int BUFB   = GB + 8192;
    constexpr int GLOADS = GB / (NW * 64 * 16);
    constexpr int WLOADS = 8192 / (NW * 64 * 16);

    __shared__ __align__(16) char sm[2 * BUFB];

    const int t = threadIdx.x;
    const int w = t >> 6, l = t & 63;
    const int wg = xcd_swz(blockIdx.x, nblocks);
    const int row0 = wg * ROWS;
    const int lr = l & 15, lhi = l >> 4;
    const int chbase = lr & 7;
    const int srcswz = (((l & 7) ^ (l >> 3)) << 4);

    const int* nbp[GLOADS];
    #pragma unroll
    for (int i = 0; i < GLOADS; ++i) {
        int rt = w * RPW + i * 8 + (l >> 3);
        nbp[i] = nbr + (size_t)(row0 + rt) * KN;
    }

    f32x4 acc[MB][4];
    #pragma unroll
    for (int a = 0; a < MB; ++a)
        #pragma unroll
        for (int b = 0; b < 4; ++b) acc[a][b] = (f32x4)0.0f;

    int idxn[GLOADS];

    // ---- prologue: stage tap 0 into buf0, prefetch idx(1) ----
    {
        int idx0[GLOADS];
        #pragma unroll
        for (int i = 0; i < GLOADS; ++i) idx0[i] = nbp[i][0];
        const char* wsrc = (const char*)Wsw;
        #pragma unroll
        for (int i = 0; i < WLOADS; ++i) {
            int off = (w * WLOADS + i) * 1024;
            gload_lds16(wsrc + off + l * 16, sm + GB + off);
        }
        #pragma unroll
        for (int i = 0; i < GLOADS; ++i) {
            const char* src = (idx0[i] >= 0)
                ? (const char*)feats + (size_t)idx0[i] * 128 + srcswz
                : (const char*)zpage + srcswz;
            gload_lds16(src, sm + (w * RPW + i * 8) * 128);
        }
        #pragma unroll
        for (int i = 0; i < GLOADS; ++i) idxn[i] = nbp[i][1];
    }

    for (int k = 0; k < KN; ++k) {
        char* cur = sm + (k & 1) * BUFB;
        char* nxt = sm + ((k + 1) & 1) * BUFB;

        __syncthreads();   // drains my stage(k); rendezvous all waves

        if (k < KN - 1) {
            const char* wsrc = (const char*)Wsw + (size_t)(k + 1) * 8192;
            #pragma unroll
            for (int i = 0; i < WLOADS; ++i) {
                int off = (w * WLOADS + i) * 1024;
                gload_lds16(wsrc + off + l * 16, nxt + GB + off);
            }
            #pragma unroll
            for (int i = 0; i < GLOADS; ++i) {
                const char* src = (idxn[i] >= 0)
                    ? (const char*)feats + (size_t)idxn[i] * 128 + srcswz
                    : (const char*)zpage + srcswz;
                gload_lds16(src, nxt + (w * RPW + i * 8) * 128);
            }
        }
        if (k < KN - 2) {
            #pragma unroll
            for (int i = 0; i < GLOADS; ++i) idxn[i] = nbp[i][k + 2];
        }

        __builtin_amdgcn_s_setprio(1);
        #pragma unroll
        for (int j0 = 0; j0 < 2; ++j0) {
            short8v af[MB], bfr[4];
            #pragma unroll
            for (int mb = 0; mb < MB; ++mb) {
                int r = w * RPW + mb * 16 + lr;
                int ch = (j0 * 4 + lhi) ^ chbase;
                af[mb] = *(const short8v*)(cur + r * 128 + ch * 16);
            }
            #pragma unroll
            for (int nb = 0; nb < 4; ++nb) {
                int c = nb * 16 + lr;
                int ch = (j0 * 4 + lhi) ^ chbase;
                bfr[nb] = *(const short8v*)(cur + GB + c * 128 + ch * 16);
            }
            #pragma unroll
            for (int mb = 0; mb < MB; ++mb)
                #pragma unroll
                for (int nb = 0; nb < 4; ++nb)
                    acc[mb][nb] = __builtin_amdgcn_mfma_f32_16x16x32_bf16(
                        af[mb], bfr[nb], acc[mb][nb], 0, 0, 0);
        }
        __builtin_amdgcn_s_setprio(0);
    }

    // ---- epilogue: +res, relu, pack 2 cols, store bf16 ----
    #pragma unroll
    for (int mb = 0; mb < MB; ++mb) {
        #pragma unroll
        for (int nb = 0; nb < 4; ++nb) {
            #pragma unroll
            for (int r = 0; r < 4; ++r) {
                int rg = row0 + w * RPW + mb * 16 + lhi * 4 + r;
                int c = nb * 16 + lr;
                float v = acc[mb][nb][r];
                if (res != nullptr) v += bf2f(res[(size_t)rg * 64 + c]);
                v = fmaxf(v, 0.0f);
                float o = __shfl_xor(v, 1);
                if (!(l & 1)) {
                    uint pk = (uint)f2bf(v) | ((uint)f2bf(o) << 16);
                    *(uint*)((char*)out + (size_t)rg * 128 + (c << 1)) = pk;
                }
            }
        }
    }
}

// ---------------------------------------------------------------------------
// MFMA head with lane-parallel softmax (LDS transpose of logits)
// ---------------------------------------------------------------------------
__global__ __launch_bounds__(256) void head_mfma_k(
    const ushort* __restrict__ G, const int* __restrict__ next_occ,
    const ushort* __restrict__ Wsmall,
    const float* __restrict__ b0a, const float* __restrict__ b1a,
    const float* __restrict__ b0b, const float* __restrict__ b1b,
    const int* __restrict__ n_points, float* __restrict__ outp)
{
    __shared__ __align__(16) char sm[32768 + 22528 + 640 + 8704];
    char* sG = sm;
    char* sH = sm + 16384;
    char* sWs = sm + 32768;
    float* sBf = (float*)(sm + 32768 + 22528);
    float* sL  = (float*)(sm + 32768 + 22528 + 640);   // [128][17] f32

    const int t = threadIdx.x;
    const int w = t >> 6, l = t & 63;
    const int row0 = blockIdx.x * 128;
    const int lr = l & 15, lhi = l >> 4;
    const int wr0 = w * 32;
    const int myrow = wr0 + (l & 31);
    const int occ_l = next_occ[row0 + myrow];

    #pragma unroll
    for (int i = 0; i < 4; ++i) {
        int rt = w * 32 + i * 8 + (l >> 3);
        int row = row0 + rt;
        gload_lds16((const char*)G + (size_t)row * 128 + (((l & 7) ^ (rt & 7)) << 4),
                    sG + (w * 32 + i * 8) * 128);
    }
    for (int i = w; i < 22; i += 4)
        gload_lds16((const char*)Wsmall + i * 1024 + l * 16, sWs + i * 1024);
    if (t < 64)                 sBf[t] = b0a[t];
    else if (t < 128)           sBf[t] = b1a[t - 64];
    else if (t < 144)           sBf[128 + (t - 128)] = b0b[t - 128];
    else if (t < 160)           sBf[144 + (t - 144)] = b1b[t - 144];
    __syncthreads();

    float bacc = 0.0f;
    f32x4 lg[2];

    // ======== stage 0 ========
    {
        f32x4 acc[2][4];
        #pragma unroll
        for (int a = 0; a < 2; ++a)
            #pragma unroll
            for (int b = 0; b < 4; ++b) acc[a][b] = (f32x4)0.0f;
        #pragma unroll
        for (int j0 = 0; j0 < 2; ++j0) {
            short8v a[2], b[4];
            #pragma unroll
            for (int mb = 0; mb < 2; ++mb) {
                int r = wr0 + mb * 16 + lr;
                int ch = (j0 * 4 + lhi) ^ (r & 7);
                a[mb] = *(const short8v*)(sG + r * 128 + ch * 16);
            }
            #pragma unroll
            for (int nb = 0; nb < 4; ++nb) {
                int c = nb * 16 + lr;
                int ch = (j0 * 4 + lhi) ^ (c & 7);
                b[nb] = *(const short8v*)(sWs + c * 128 + ch * 16);   // W0aT
            }
            #pragma unroll
            for (int mb = 0; mb < 2; ++mb)
                #pragma unroll
                for (int nb = 0; nb < 4; ++nb)
                    acc[mb][nb] = __builtin_amdgcn_mfma_f32_16x16x32_bf16(
                        a[mb], b[nb], acc[mb][nb], 0, 0, 0);
        }
        #pragma unroll
        for (int mb = 0; mb < 2; ++mb)
            #pragma unroll
            for (int nb = 0; nb < 4; ++nb) {
                float bias = sBf[nb * 16 + lr];
                #pragma unroll
                for (int r = 0; r < 4; ++r) {
                    int row = wr0 + mb * 16 + lhi * 4 + r;
                    int j = nb * 16 + lr;
                    float v = fmaxf(acc[mb][nb][r] + bias, 0.0f);
                    float o = __shfl_xor(v, 1);
                    if (!(l & 1)) {
                        uint pk = (uint)f2bf(v) | ((uint)f2bf(o) << 16);
                        *(uint*)(sH + row * 128 + (((j >> 3) ^ (row & 7)) << 4)
                                 + (j & 7) * 2) = pk;
                    }
                }
            }
        lg[0] = (f32x4)0.0f; lg[1] = (f32x4)0.0f;
        #pragma unroll
        for (int j0 = 0; j0 < 2; ++j0) {
            short8v a[2], b;
            #pragma unroll
            for (int mb = 0; mb < 2; ++mb) {
                int r = wr0 + mb * 16 + lr;
                int ch = (j0 * 4 + lhi) ^ (r & 7);
                a[mb] = *(const short8v*)(sH + r * 128 + ch * 16);
            }
            {
                int c = lr;
                int ch = (j0 * 4 + lhi) ^ (c & 7);
                b = *(const short8v*)(sWs + 16384 + c * 128 + ch * 16); // W0bT
            }
            #pragma unroll
            for (int mb = 0; mb < 2; ++mb)
                lg[mb] = __builtin_amdgcn_mfma_f32_16x16x32_bf16(a[mb], b, lg[mb], 0, 0, 0);
        }
        #pragma unroll
        for (int mb = 0; mb < 2; ++mb)
            #pragma unroll
            for (int r = 0; r < 4; ++r)
                sL[(wr0 + mb * 16 + lhi * 4 + r) * 17 + lr] = lg[mb][r] + sBf[128 + lr];
        asm volatile("s_waitcnt lgkmcnt(0)" ::: "memory");
        __builtin_amdgcn_sched_barrier(0);
        {
            int tgt = occ_l & 15;
            float lv[16], mx = -1e30f;
            #pragma unroll
            for (int c = 0; c < 16; ++c) {
                lv[c] = sL[myrow * 17 + c];
                mx = fmaxf(mx, lv[c]);
            }
            float ssum = 0.0f, lt = lv[0];
            #pragma unroll
            for (int c = 0; c < 16; ++c) {
                ssum += __expf(lv[c] - mx);
                lt = (c == tgt) ? lv[c] : lt;
            }
            float p = __expf(lt - mx) / ssum;
            float bits = fminf(fmaxf(-log2f(p + 1e-10f), 0.0f), 50.0f);
            if (l < 32) bacc += bits;
        }
    }

    // ======== stage 1 ========
    {
        f32x4 acc1[2][4];
        #pragma unroll
        for (int a = 0; a < 2; ++a)
            #pragma unroll
            for (int b = 0; b < 4; ++b) acc1[a][b] = (f32x4)0.0f;
        #pragma unroll
        for (int j0 = 0; j0 < 2; ++j0) {
            short8v a[2], b[4];
            #pragma unroll
            for (int mb = 0; mb < 2; ++mb) {
                int rloc = wr0 + mb * 16 + lr;
                int low = next_occ[row0 + rloc] & 15;
                int ch = (j0 * 4 + lhi) ^ (rloc & 7);
                short8v g8 = *(const short8v*)(sG + rloc * 128 + ch * 16);
                int che = (j0 * 4 + lhi) ^ (low & 7);
                short8v e8 = *(const short8v*)(sWs + 20480 + low * 128 + che * 16); // s1b
                #pragma unroll
                for (int e = 0; e < 8; ++e) {
                    float f = bf2f((ushort)g8[e]) + bf2f((ushort)e8[e]);
                    a[mb][e] = (short)f2bf(f);
                }
            }
            #pragma unroll
            for (int nb = 0; nb < 4; ++nb) {
                int c = nb * 16 + lr;
                int ch = (j0 * 4 + lhi) ^ (c & 7);
                b[nb] = *(const short8v*)(sWs + 8192 + c * 128 + ch * 16);  // W1aT
            }
            #pragma unroll
            for (int mb = 0; mb < 2; ++mb)
                #pragma unroll
                for (int nb = 0; nb < 4; ++nb)
                    acc1[mb][nb] = __builtin_amdgcn_mfma_f32_16x16x32_bf16(
                        a[mb], b[nb], acc1[mb][nb], 0, 0, 0);
        }
        #pragma unroll
        for (int mb = 0; mb < 2; ++mb)
            #pragma unroll
            for (int nb = 0; nb < 4; ++nb) {
                float bias = sBf[64 + nb * 16 + lr];
                #pragma unroll
                for (int r = 0; r < 4; ++r) {
                    int row = wr0 + mb * 16 + lhi * 4 + r;
                    int j = nb * 16 + lr;
                    float v = fmaxf(acc1[mb][nb][r] + bias, 0.0f);
                    float o = __shfl_xor(v, 1);
                    if (!(l & 1)) {
                        uint pk = (uint)f2bf(v) | ((uint)f2bf(o) << 16);
                        *(uint*)(sH + row * 128 + (((j >> 3) ^ (row & 7)) << 4)
                                 + (j & 7) * 2) = pk;
                    }
                }
            }
        lg[0] = (f32x4)0.0f; lg[1] = (f32x4)0.0f;
        #pragma unroll
        for (int j0 = 0; j0 < 2; ++j0) {
            short8v a[2], b;
            #pragma unroll
            for (int mb = 0; mb < 2; ++mb) {
                int r = wr0 + mb * 16 + lr;
                int ch = (j0 * 4 + lhi) ^ (r & 7);
                a[mb] = *(const short8v*)(sH + r * 128 + ch * 16);
            }
            {
                int c = lr;
                int ch = (j0 * 4 + lhi) ^ (c & 7);
                b = *(const short8v*)(sWs + 18432 + c * 128 + ch * 16); // W1bT
            }
            #pragma unroll
            for (int mb = 0; mb < 2; ++mb)
                lg[mb] = __builtin_amdgcn_mfma_f32_16x16x32_bf16(a[mb], b, lg[mb], 0, 0, 0);
        }
        #pragma unroll
        for (int mb = 0; mb < 2; ++mb)
            #pragma unroll
            for (int r = 0; r < 4; ++r)
                sL[(wr0 + mb * 16 + lhi * 4 + r) * 17 + lr] = lg[mb][r] + sBf[144 + lr];
        asm volatile("s_waitcnt lgkmcnt(0)" ::: "memory");
        __builtin_amdgcn_sched_barrier(0);
        {
            int tgt = occ_l >> 4;
            float lv[16], mx = -1e30f;
            #pragma unroll
            for (int c = 0; c < 16; ++c) {
                lv[c] = sL[myrow * 17 + c];
                mx = fmaxf(mx, lv[c]);
            }
            float ssum = 0.0f, lt = lv[0];
            #pragma unroll
            for (int c = 0; c < 16; ++c) {
                ssum += __expf(lv[c] - mx);
                lt = (c == tgt) ? lv[c] : lt;
            }
            float p = __expf(lt - mx) / ssum;
            float bits = fminf(fmaxf(-log2f(p + 1e-10f), 0.0f), 50.0f);
            if (l < 32) bacc += bits;
        }
    }

    #pragma unroll
    for (int s = 1; s < 64; s <<= 1) bacc += __shfl_xor(bacc, s);
    if (l == 0) atomicAdd(outp, bacc / (float)(*n_points));
}

// ---------------------------------------------------------------------------
extern "C" void kernel_launch(void* const* d_in, const int* in_sizes, int n_in,
                              void* d_out, int out_size, void* d_ws, size_t ws_size,
                              hipStream_t stream)
{
    const float* prior_emb = (const float*)d_in[0];
    const float* temb8     = (const float*)d_in[1];
    const float* Wp        = (const float*)d_in[2];
    const float* Wt        = (const float*)d_in[3];
    const float* W0a       = (const float*)d_in[4];
    const float* b0a       = (const float*)d_in[5];
    const float* W0b       = (const float*)d_in[6];
    const float* b0b       = (const float*)d_in[7];
    const float* W1a       = (const float*)d_in[8];
    const float* b1a       = (const float*)d_in[9];
    const float* W1b       = (const float*)d_in[10];
    const float* b1b       = (const float*)d_in[11];
    const float* s1_emb    = (const float*)d_in[12];
    const int*   curr_occ  = (const int*)d_in[13];
    const int*   next_occ  = (const int*)d_in[14];
    const int*   next_oct  = (const int*)d_in[15];
    const int*   parent    = (const int*)d_in[16];
    const int*   nbr_curr  = (const int*)d_in[17];
    const int*   nbr_next  = (const int*)d_in[18];
    const int*   n_points  = (const int*)d_in[19];
    float* out = (float*)d_out;

    char* wsb = (char*)d_ws;
    ushort* zpage = (ushort*)wsb;
    size_t off = 256;
    ushort* WpT = (ushort*)(wsb + off); off += (size_t)135 * 4096 * 2;
    ushort* WtT = (ushort*)(wsb + off); off += (size_t)135 * 4096 * 2;
    ushort* Wsmall = (ushort*)(wsb + off);
    ushort* W0aT = Wsmall;
    ushort* W1aT = Wsmall + 4096;
    ushort* W0bT = Wsmall + 8192;
    ushort* W1bT = Wsmall + 9216;
    ushort* s1bT = Wsmall + 10240;
    off += 11264 * 2;
    off = (off + 255) & ~(size_t)255;
    ushort* fA = (ushort*)(wsb + off); off += (size_t)NP1 * 64 * 2;
    ushort* fB = (ushort*)(wsb + off); off += (size_t)NP1 * 64 * 2;
    ushort* fC = (ushort*)(wsb + off); off += (size_t)NP1 * 64 * 2;
    ushort* gA = (ushort*)(wsb + off); off += (size_t)NP2 * 64 * 2;
    ushort* gB = (ushort*)(wsb + off); off += (size_t)NP2 * 64 * 2;
    ushort* gC = (ushort*)(wsb + off); off += (size_t)NP2 * 64 * 2;

    hipMemsetAsync(d_out, 0, sizeof(float), stream);
    hipMemsetAsync(zpage, 0, 256, stream);

    prep_wT_k<<<(135 * 4096 + 255) / 256, 256, 0, stream>>>(Wp, WpT, 135);
    prep_wT_k<<<(135 * 4096 + 255) / 256, 256, 0, stream>>>(Wt, WtT, 135);
    prep_wT_k<<<16, 256, 0, stream>>>(W0a, W0aT, 1);
    prep_wT_k<<<16, 256, 0, stream>>>(W1a, W1aT, 1);
    prep_wbT_k<<<4, 256, 0, stream>>>(W0b, W0bT);
    prep_wbT_k<<<4, 256, 0, stream>>>(W1b, W1bT);
    prep_s1_k<<<4, 256, 0, stream>>>(s1_emb, s1bT);

    gather_curr_k<<<(NP1 * 32 + 255) / 256, 256, 0, stream>>>(prior_emb, curr_occ, fA);

    const size_t WT = (size_t)KN * 4096;
    // N1: <2,1> 32 rows/block, 625 blocks, 24 KB LDS -> 6 blk/CU cap
    // N2: <8,1> 128 rows/block, 625 blocks, 16 rows/wave (5000 waves),
    //     48 KB LDS -> 3 blk/CU = 24 waves/CU (75% cap)
    spconv_db_k<2,1><<<625, 128, 0, stream>>>(fA, nbr_curr, WpT + 0 * WT, nullptr, fB, zpage, 625);
    spconv_db_k<2,1><<<625, 128, 0, stream>>>(fB, nbr_curr, WpT + 1 * WT, nullptr, fC, zpage, 625);
    spconv_db_k<2,1><<<625, 128, 0, stream>>>(fC, nbr_curr, WpT + 2 * WT, fB,      fA, zpage, 625);
    spconv_db_k<2,1><<<625, 128, 0, stream>>>(fA, nbr_curr, WpT + 3 * WT, nullptr, fC, zpage, 625);
    spconv_db_k<2,1><<<625, 128, 0, stream>>>(fC, nbr_curr, WpT + 4 * WT, fA,      fB, zpage, 625);

    gather_next_k<<<(NP2 * 32 + 255) / 256, 256, 0, stream>>>(fB, parent, next_oct, temb8, gA);

    spconv_db_k<8,1><<<625, 512, 0, stream>>>(gA, nbr_next, WtT + 0 * WT, nullptr, gB, zpage, 625);
    spconv_db_k<8,1><<<625, 512, 0, stream>>>(gB, nbr_next, WtT + 1 * WT, nullptr, gC, zpage, 625);
    spconv_db_k<8,1><<<625, 512, 0, stream>>>(gC, nbr_next, WtT + 2 * WT, gB,      gA, zpage, 625);
    spconv_db_k<8,1><<<625, 512, 0, stream>>>(gA, nbr_next, WtT + 3 * WT, nullptr, gC, zpage, 625);
    spconv_db_k<8,1><<<625, 512, 0, stream>>>(gC, nbr_next, WtT + 4 * WT, gA,      gB, zpage, 625);

    head_mfma_k<<<625, 256, 0, stream>>>(gB, next_occ, Wsmall,
                                         b0a, b1a, b0b, b1b, n_points, out);
}